// Round 1
// baseline (388.886 us; speedup 1.0000x reference)
//
#include <hip/hip_runtime.h>
#include <cstdint>
#include <cstddef>

#define IN_DIM 128
#define HID 32
#define NH 4
#define OUT_DIM 128
#define NEG 0.2f
#define NN 8   // nodes per 128-thread slot in node_proj

static __device__ __forceinline__ float leaky(float v) { return v > 0.f ? v : NEG * v; }

// K0: al_vec[t][i] = sum_j al_w[t][i][j]  (and same for ar)
__global__ void alvec_kernel(const float* __restrict__ al_w, const float* __restrict__ ar_w,
                             float* __restrict__ alvec, float* __restrict__ arvec) {
    int id = threadIdx.x;
    if (id >= 2 * 5 * HID) return;
    int which = id >= 5 * HID;
    int r = id - which * 5 * HID;          // r = t*32 + i
    const float* srcw = which ? ar_w : al_w;
    int t = r >> 5, i = r & 31;
    const float* p = srcw + (size_t)t * HID * HID + (size_t)i * HID;
    float s = 0.f;
    for (int jj = 0; jj < HID; ++jj) s += p[jj];
    (which ? arvec : alvec)[r] = s;
}

// K1: h_ws[n] = x[n] @ W_typed[ntype[n]];  out[n] = x[n] @ W_res + b_res  (pre-relu residual)
__global__ void node_proj_kernel(const float* __restrict__ x, const int* __restrict__ ntype,
                                 const float* __restrict__ Wt, const float* __restrict__ Wres,
                                 const float* __restrict__ bres,
                                 float* __restrict__ h_ws, float* __restrict__ out, int n_nodes) {
    __shared__ float xs[2 * NN][IN_DIM];
    int tid = threadIdx.x;
    int slot = tid >> 7, j = tid & 127;
    int base = blockIdx.x * (2 * NN);
    for (int idx = tid; idx < 2 * NN * IN_DIM; idx += 256) {
        int row = idx >> 7, col = idx & 127;
        int n = base + row;
        xs[row][col] = (n < n_nodes) ? x[(size_t)n * IN_DIM + col] : 0.f;
    }
    __syncthreads();

    // typed projection, per node (W differs per node type)
    for (int k = 0; k < NN; ++k) {
        int n = base + slot * NN + k;
        if (n >= n_nodes) break;
        int t = ntype[n];
        const float* W = Wt + (size_t)t * IN_DIM * OUT_DIM + j;
        const float* xr = xs[slot * NN + k];
        float acc = 0.f;
#pragma unroll 8
        for (int i = 0; i < IN_DIM; ++i) acc += xr[i] * W[(size_t)i * OUT_DIM];
        h_ws[(size_t)n * OUT_DIM + j] = acc;
    }

    // residual: reuse each W_res element across NN nodes
    float racc[NN];
#pragma unroll
    for (int k = 0; k < NN; ++k) racc[k] = bres[j];
    for (int i = 0; i < IN_DIM; ++i) {
        float w = Wres[(size_t)i * OUT_DIM + j];
#pragma unroll
        for (int k = 0; k < NN; ++k) racc[k] += xs[slot * NN + k][i] * w;
    }
    for (int k = 0; k < NN; ++k) {
        int n = base + slot * NN + k;
        if (n < n_nodes) out[(size_t)n * OUT_DIM + j] = racc[k];
    }
}

// K2: hl[n*4+h] = h[n,h,:]·alvec[t],  hr likewise
__global__ void hlr_kernel(const float* __restrict__ h_ws, const int* __restrict__ ntype,
                           const float* __restrict__ alvec, const float* __restrict__ arvec,
                           float* __restrict__ hl, float* __restrict__ hr, int n_nodes) {
    int id = blockIdx.x * 256 + threadIdx.x;
    if (id >= n_nodes * NH) return;
    int n = id >> 2, h = id & 3;
    int t = ntype[n];
    const float4* hp = (const float4*)(h_ws + (size_t)n * OUT_DIM + h * HID);
    const float4* av = (const float4*)(alvec + t * HID);
    const float4* bv = (const float4*)(arvec + t * HID);
    float sl = 0.f, sr = 0.f;
#pragma unroll
    for (int i = 0; i < HID / 4; ++i) {
        float4 v = hp[i], a = av[i], b = bv[i];
        sl += v.x * a.x + v.y * a.y + v.z * a.z + v.w * a.w;
        sr += v.x * b.x + v.y * b.y + v.z * b.z + v.w * b.w;
    }
    hl[id] = sl;
    hr[id] = sr;
}

// K3: histogram of dst
__global__ void hist_kernel(const int* __restrict__ dst, int* __restrict__ counts, int E) {
    int e = blockIdx.x * 256 + threadIdx.x;
    if (e < E) atomicAdd(&counts[dst[e]], 1);
}

// K4a: per-block exclusive scan + block sums
__global__ void scan1_kernel(const int* __restrict__ counts, int* __restrict__ offs,
                             int* __restrict__ bsums, int n) {
    __shared__ int tmp[256];
    int tid = threadIdx.x, gid = blockIdx.x * 256 + tid;
    int v = (gid < n) ? counts[gid] : 0;
    tmp[tid] = v;
    __syncthreads();
    for (int o = 1; o < 256; o <<= 1) {
        int add = (tid >= o) ? tmp[tid - o] : 0;
        __syncthreads();
        tmp[tid] += add;
        __syncthreads();
    }
    if (gid < n) offs[gid] = tmp[tid] - v;   // exclusive
    if (tid == 255) bsums[blockIdx.x] = tmp[255];
}

// K4b: single-block exclusive scan of block sums (nb <= 256)
__global__ void scan2_kernel(int* __restrict__ bsums, int nb) {
    __shared__ int tmp[256];
    int tid = threadIdx.x;
    int v = (tid < nb) ? bsums[tid] : 0;
    tmp[tid] = v;
    __syncthreads();
    for (int o = 1; o < 256; o <<= 1) {
        int add = (tid >= o) ? tmp[tid - o] : 0;
        __syncthreads();
        tmp[tid] += add;
        __syncthreads();
    }
    if (tid < nb) bsums[tid] = tmp[tid] - v;
}

// K4c: add block offsets back
__global__ void scan3_kernel(int* __restrict__ offs, const int* __restrict__ bsums, int n) {
    int gid = blockIdx.x * 256 + threadIdx.x;
    if (gid < n) offs[gid] += bsums[blockIdx.x];
}

// K5: scatter edges into CSR-by-dst; pre-gather hl[src] per edge
__global__ void scatter_kernel(const int* __restrict__ src, const int* __restrict__ dst,
                               const int* __restrict__ offs, int* __restrict__ cursor,
                               const float4* __restrict__ hl4, int* __restrict__ src_sorted,
                               float4* __restrict__ el_sorted, int E) {
    int e = blockIdx.x * 256 + threadIdx.x;
    if (e >= E) return;
    int d = dst[e];
    int pos = offs[d] + atomicAdd(&cursor[d], 1);
    int sv = src[e];
    src_sorted[pos] = sv;
    el_sorted[pos] = hl4[sv];
}

// K6: one wave per dst node: softmax over incoming edges + weighted aggregate + fused epilogue
__global__ void agg_kernel(const int* __restrict__ offs, const int* __restrict__ counts,
                           const int* __restrict__ src_sorted, const float4* __restrict__ el_sorted,
                           const float4* __restrict__ hr4, const float* __restrict__ h_ws,
                           float* __restrict__ out, int n_nodes) {
    int wid = (int)(((size_t)blockIdx.x * blockDim.x + threadIdx.x) >> 6);
    int lane = threadIdx.x & 63;
    if (wid >= n_nodes) return;
    int n = wid;
    int ofs = offs[n], deg = counts[n];
    int head = lane & 3, d0 = lane >> 2;
    float acc0 = 0.f, acc1 = 0.f;

    if (deg > 0) {
        float4 hr = hr4[n];
        // pass A: per-head max
        float m0 = -1e30f, m1 = -1e30f, m2 = -1e30f, m3 = -1e30f;
        for (int k = lane; k < deg; k += 64) {
            float4 el = el_sorted[ofs + k];
            m0 = fmaxf(m0, leaky(el.x + hr.x));
            m1 = fmaxf(m1, leaky(el.y + hr.y));
            m2 = fmaxf(m2, leaky(el.z + hr.z));
            m3 = fmaxf(m3, leaky(el.w + hr.w));
        }
        for (int o = 32; o > 0; o >>= 1) {
            m0 = fmaxf(m0, __shfl_xor(m0, o));
            m1 = fmaxf(m1, __shfl_xor(m1, o));
            m2 = fmaxf(m2, __shfl_xor(m2, o));
            m3 = fmaxf(m3, __shfl_xor(m3, o));
        }
        // pass B: per-head sum of exp
        float s0 = 0.f, s1 = 0.f, s2 = 0.f, s3 = 0.f;
        for (int k = lane; k < deg; k += 64) {
            float4 el = el_sorted[ofs + k];
            s0 += expf(leaky(el.x + hr.x) - m0);
            s1 += expf(leaky(el.y + hr.y) - m1);
            s2 += expf(leaky(el.z + hr.z) - m2);
            s3 += expf(leaky(el.w + hr.w) - m3);
        }
        for (int o = 32; o > 0; o >>= 1) {
            s0 += __shfl_xor(s0, o);
            s1 += __shfl_xor(s1, o);
            s2 += __shfl_xor(s2, o);
            s3 += __shfl_xor(s3, o);
        }
        float mh = head == 0 ? m0 : head == 1 ? m1 : head == 2 ? m2 : m3;
        float sh = head == 0 ? s0 : head == 1 ? s1 : head == 2 ? s2 : s3;
        float hrh = head == 0 ? hr.x : head == 1 ? hr.y : head == 2 ? hr.z : hr.w;
        float inv_s = 1.f / sh;
        // pass C: serial over edges, all 64 lanes load this edge's h[src] row
        for (int k = 0; k < deg; ++k) {
            int sv = src_sorted[ofs + k];
            float4 el = el_sorted[ofs + k];
            float elh = head == 0 ? el.x : head == 1 ? el.y : head == 2 ? el.z : el.w;
            float alpha = expf(leaky(elh + hrh) - mh) * inv_s;
            const float* hrow = h_ws + (size_t)sv * OUT_DIM + head * HID;
            acc0 += alpha * hrow[d0];
            acc1 += alpha * hrow[d0 + 16];
        }
    }
    // epilogue: out[n, j] = relu(agg[n, h=j&3, d=j>>2] + res[n, j]); lane owns j=lane and j=lane+64
    size_t ob = (size_t)n * OUT_DIM;
    out[ob + lane]      = fmaxf(acc0 + out[ob + lane], 0.f);
    out[ob + 64 + lane] = fmaxf(acc1 + out[ob + 64 + lane], 0.f);
}

extern "C" void kernel_launch(void* const* d_in, const int* in_sizes, int n_in,
                              void* d_out, int out_size, void* d_ws, size_t ws_size,
                              hipStream_t stream) {
    const float* x     = (const float*)d_in[0];
    const int*   ntype = (const int*)d_in[1];
    // d_in[2] = etype (unused by reference)
    const int*   src   = (const int*)d_in[3];
    const int*   dst   = (const int*)d_in[4];
    const float* Wt    = (const float*)d_in[5];
    const float* alw   = (const float*)d_in[6];
    const float* arw   = (const float*)d_in[7];
    const float* Wres  = (const float*)d_in[8];
    const float* bres  = (const float*)d_in[9];
    float* out = (float*)d_out;
    int N = in_sizes[1];
    int E = in_sizes[3];

    char* ws = (char*)d_ws;
    size_t off = 0;
    auto alloc = [&](size_t bytes) -> char* {
        char* p = ws + off;
        off += (bytes + 255) & ~(size_t)255;
        return p;
    };
    float*  h_ws       = (float*)alloc((size_t)N * OUT_DIM * 4);
    float*  hl         = (float*)alloc((size_t)N * NH * 4);
    float*  hr         = (float*)alloc((size_t)N * NH * 4);
    float*  alv        = (float*)alloc(5 * HID * 4);
    float*  arv        = (float*)alloc(5 * HID * 4);
    int*    counts     = (int*)alloc((size_t)N * 4);
    int*    offs       = (int*)alloc((size_t)N * 4);
    int*    cursor     = (int*)alloc((size_t)N * 4);
    int*    bsums      = (int*)alloc(256 * 4);
    int*    src_sorted = (int*)alloc((size_t)E * 4);
    float4* el_sorted  = (float4*)alloc((size_t)E * 16);

    hipMemsetAsync(counts, 0, (size_t)N * 4, stream);
    hipMemsetAsync(cursor, 0, (size_t)N * 4, stream);

    alvec_kernel<<<1, 320, 0, stream>>>(alw, arw, alv, arv);

    int nb1 = (N + 2 * NN - 1) / (2 * NN);
    node_proj_kernel<<<nb1, 256, 0, stream>>>(x, ntype, Wt, Wres, bres, h_ws, out, N);

    hlr_kernel<<<(N * NH + 255) / 256, 256, 0, stream>>>(h_ws, ntype, alv, arv, hl, hr, N);

    hist_kernel<<<(E + 255) / 256, 256, 0, stream>>>(dst, counts, E);

    int nbs = (N + 255) / 256;   // 196 <= 256, fits single-block scan2
    scan1_kernel<<<nbs, 256, 0, stream>>>(counts, offs, bsums, N);
    scan2_kernel<<<1, 256, 0, stream>>>(bsums, nbs);
    scan3_kernel<<<nbs, 256, 0, stream>>>(offs, bsums, N);

    scatter_kernel<<<(E + 255) / 256, 256, 0, stream>>>(src, dst, offs, cursor,
                                                        (const float4*)hl, src_sorted, el_sorted, E);

    agg_kernel<<<(N + 3) / 4, 256, 0, stream>>>(offs, counts, src_sorted, el_sorted,
                                                (const float4*)hr, h_ws, out, N);
}

// Round 2
// 337.473 us; speedup vs baseline: 1.1523x; 1.1523x over previous
//
#include <hip/hip_runtime.h>
#include <cstdint>
#include <cstddef>

#define IN_DIM 128
#define HID 32
#define NH 4
#define OUT_DIM 128
#define NEG 0.2f
#define NT 5
#define BPN 32   // nodes per block in node_proj_typed

static __device__ __forceinline__ float leaky(float v) { return v > 0.f ? v : NEG * v; }

// K0: al_vec[t][i] = sum_j al_w[t][i][j]  (and same for ar)
__global__ void alvec_kernel(const float* __restrict__ al_w, const float* __restrict__ ar_w,
                             float* __restrict__ alvec, float* __restrict__ arvec) {
    int id = threadIdx.x;
    if (id >= 2 * NT * HID) return;
    int which = id >= NT * HID;
    int r = id - which * NT * HID;          // r = t*32 + i
    const float* srcw = which ? ar_w : al_w;
    int t = r >> 5, i = r & 31;
    const float* p = srcw + (size_t)t * HID * HID + (size_t)i * HID;
    float s = 0.f;
    for (int jj = 0; jj < HID; ++jj) s += p[jj];
    (which ? arvec : alvec)[r] = s;
}

// ---- node type counting sort ----
__global__ void type_hist_kernel(const int* __restrict__ ntype, int* __restrict__ tcnt, int n) {
    __shared__ int lc[NT];
    int tid = threadIdx.x;
    if (tid < NT) lc[tid] = 0;
    __syncthreads();
    int gid = blockIdx.x * 256 + tid;
    if (gid < n) atomicAdd(&lc[ntype[gid]], 1);
    __syncthreads();
    if (tid < NT && lc[tid] > 0) atomicAdd(&tcnt[tid], lc[tid]);
}

// single-thread: tstart (exclusive scan) and padded block offsets pb
__global__ void tsetup_kernel(const int* __restrict__ tcnt, int* __restrict__ tstart,
                              int* __restrict__ pb) {
    int s = 0, b = 0;
    for (int t = 0; t < NT; ++t) {
        tstart[t] = s;
        pb[t] = b;
        s += tcnt[t];
        b += (tcnt[t] + BPN - 1) / BPN;
    }
    tstart[NT] = s;
    pb[NT] = b;
}

__global__ void type_scatter_kernel(const int* __restrict__ ntype, const int* __restrict__ tstart,
                                    int* __restrict__ tcur, int* __restrict__ order, int n) {
    __shared__ int lc[NT];
    __shared__ int gb[NT];
    int tid = threadIdx.x;
    if (tid < NT) lc[tid] = 0;
    __syncthreads();
    int gid = blockIdx.x * 256 + tid;
    int t = -1, rank = 0;
    if (gid < n) {
        t = ntype[gid];
        rank = atomicAdd(&lc[t], 1);
    }
    __syncthreads();
    if (tid < NT && lc[tid] > 0) gb[tid] = atomicAdd(&tcur[tid], lc[tid]);
    __syncthreads();
    if (gid < n) order[tstart[t] + gb[t] + rank] = gid;
}

// K1: typed projection + residual, blocks type-homogeneous via `order`
// 256 threads = 4 waves; wave w owns nodes w*8..w*8+7 of the block's 32;
// lane owns output cols lane and lane+64.
__global__ void node_proj_typed_kernel(const float* __restrict__ x, const int* __restrict__ order,
                                       const int* __restrict__ tstart, const int* __restrict__ tcnt,
                                       const int* __restrict__ pb,
                                       const float* __restrict__ Wt, const float* __restrict__ Wres,
                                       const float* __restrict__ bres,
                                       float* __restrict__ h_ws, float* __restrict__ out) {
    __shared__ float xs[BPN][IN_DIM];
    __shared__ int nids[BPN];
    __shared__ int spb[NT + 1];
    int tid = threadIdx.x;
    if (tid < NT + 1) spb[tid] = pb[tid];
    __syncthreads();
    int b = blockIdx.x;
    if (b >= spb[NT]) return;
    int t = 0;
    while (b >= spb[t + 1]) ++t;
    int lb = b - spb[t];
    int base = lb * BPN;        // within type t
    int cnt = tcnt[t];
    int ts = tstart[t];
    if (tid < BPN) nids[tid] = (base + tid < cnt) ? order[ts + base + tid] : -1;
    __syncthreads();

    // stage 32 x-rows into LDS (float4)
    for (int idx = tid; idx < BPN * (IN_DIM / 4); idx += 256) {
        int row = idx >> 5, c4 = idx & 31;
        int n = nids[row];
        float4 v = make_float4(0.f, 0.f, 0.f, 0.f);
        if (n >= 0) v = ((const float4*)(x + (size_t)n * IN_DIM))[c4];
        ((float4*)xs[row])[c4] = v;
    }
    __syncthreads();

    int wslot = tid >> 6, lane = tid & 63;
    const float* wtp = Wt + (size_t)t * IN_DIM * OUT_DIM;

    float at0[8], at1[8], ar0[8], ar1[8];
#pragma unroll
    for (int k = 0; k < 8; ++k) { at0[k] = at1[k] = ar0[k] = ar1[k] = 0.f; }

    for (int i = 0; i < IN_DIM; ++i) {
        float wt0 = wtp[(size_t)i * OUT_DIM + lane];
        float wt1 = wtp[(size_t)i * OUT_DIM + lane + 64];
        float wr0 = Wres[(size_t)i * OUT_DIM + lane];
        float wr1 = Wres[(size_t)i * OUT_DIM + lane + 64];
#pragma unroll
        for (int k = 0; k < 8; ++k) {
            float xv = xs[wslot * 8 + k][i];
            at0[k] += xv * wt0;
            at1[k] += xv * wt1;
            ar0[k] += xv * wr0;
            ar1[k] += xv * wr1;
        }
    }

    float b0 = bres[lane], b1 = bres[lane + 64];
#pragma unroll
    for (int k = 0; k < 8; ++k) {
        int n = nids[wslot * 8 + k];
        if (n < 0) continue;
        size_t ob = (size_t)n * OUT_DIM;
        h_ws[ob + lane]      = at0[k];
        h_ws[ob + lane + 64] = at1[k];
        out[ob + lane]       = ar0[k] + b0;
        out[ob + lane + 64]  = ar1[k] + b1;
    }
}

// K2: hl[n*4+h] = h[n,h,:]·alvec[t],  hr likewise
__global__ void hlr_kernel(const float* __restrict__ h_ws, const int* __restrict__ ntype,
                           const float* __restrict__ alvec, const float* __restrict__ arvec,
                           float* __restrict__ hl, float* __restrict__ hr, int n_nodes) {
    int id = blockIdx.x * 256 + threadIdx.x;
    if (id >= n_nodes * NH) return;
    int n = id >> 2, h = id & 3;
    int t = ntype[n];
    const float4* hp = (const float4*)(h_ws + (size_t)n * OUT_DIM + h * HID);
    const float4* av = (const float4*)(alvec + t * HID);
    const float4* bv = (const float4*)(arvec + t * HID);
    float sl = 0.f, sr = 0.f;
#pragma unroll
    for (int i = 0; i < HID / 4; ++i) {
        float4 v = hp[i], a = av[i], b = bv[i];
        sl += v.x * a.x + v.y * a.y + v.z * a.z + v.w * a.w;
        sr += v.x * b.x + v.y * b.y + v.z * b.z + v.w * b.w;
    }
    hl[id] = sl;
    hr[id] = sr;
}

// K3: histogram of dst
__global__ void hist_kernel(const int* __restrict__ dst, int* __restrict__ counts, int E) {
    int e = blockIdx.x * 256 + threadIdx.x;
    if (e < E) atomicAdd(&counts[dst[e]], 1);
}

// K4a: per-block exclusive scan + block sums
__global__ void scan1_kernel(const int* __restrict__ counts, int* __restrict__ offs,
                             int* __restrict__ bsums, int n) {
    __shared__ int tmp[256];
    int tid = threadIdx.x, gid = blockIdx.x * 256 + tid;
    int v = (gid < n) ? counts[gid] : 0;
    tmp[tid] = v;
    __syncthreads();
    for (int o = 1; o < 256; o <<= 1) {
        int add = (tid >= o) ? tmp[tid - o] : 0;
        __syncthreads();
        tmp[tid] += add;
        __syncthreads();
    }
    if (gid < n) offs[gid] = tmp[tid] - v;   // exclusive
    if (tid == 255) bsums[blockIdx.x] = tmp[255];
}

// K4b: single-block exclusive scan of block sums (nb <= 256)
__global__ void scan2_kernel(int* __restrict__ bsums, int nb) {
    __shared__ int tmp[256];
    int tid = threadIdx.x;
    int v = (tid < nb) ? bsums[tid] : 0;
    tmp[tid] = v;
    __syncthreads();
    for (int o = 1; o < 256; o <<= 1) {
        int add = (tid >= o) ? tmp[tid - o] : 0;
        __syncthreads();
        tmp[tid] += add;
        __syncthreads();
    }
    if (tid < nb) bsums[tid] = tmp[tid] - v;
}

// K4c: add block offsets back
__global__ void scan3_kernel(int* __restrict__ offs, const int* __restrict__ bsums, int n) {
    int gid = blockIdx.x * 256 + threadIdx.x;
    if (gid < n) offs[gid] += bsums[blockIdx.x];
}

// K5: scatter edges into CSR-by-dst; pre-gather hl[src] per edge
__global__ void scatter_kernel(const int* __restrict__ src, const int* __restrict__ dst,
                               const int* __restrict__ offs, int* __restrict__ cursor,
                               const float4* __restrict__ hl4, int* __restrict__ src_sorted,
                               float4* __restrict__ el_sorted, int E) {
    int e = blockIdx.x * 256 + threadIdx.x;
    if (e >= E) return;
    int d = dst[e];
    int pos = offs[d] + atomicAdd(&cursor[d], 1);
    int sv = src[e];
    src_sorted[pos] = sv;
    el_sorted[pos] = hl4[sv];
}

// K6: one wave per dst node: softmax over incoming edges + weighted aggregate + fused epilogue
__global__ void agg_kernel(const int* __restrict__ offs, const int* __restrict__ counts,
                           const int* __restrict__ src_sorted, const float4* __restrict__ el_sorted,
                           const float4* __restrict__ hr4, const float* __restrict__ h_ws,
                           float* __restrict__ out, int n_nodes) {
    int wid = (int)(((size_t)blockIdx.x * blockDim.x + threadIdx.x) >> 6);
    int lane = threadIdx.x & 63;
    if (wid >= n_nodes) return;
    int n = wid;
    int ofs = offs[n], deg = counts[n];
    int head = lane & 3, d0 = lane >> 2;
    float acc0 = 0.f, acc1 = 0.f;

    if (deg > 0) {
        float4 hr = hr4[n];
        // pass A: per-head max
        float m0 = -1e30f, m1 = -1e30f, m2 = -1e30f, m3 = -1e30f;
        for (int k = lane; k < deg; k += 64) {
            float4 el = el_sorted[ofs + k];
            m0 = fmaxf(m0, leaky(el.x + hr.x));
            m1 = fmaxf(m1, leaky(el.y + hr.y));
            m2 = fmaxf(m2, leaky(el.z + hr.z));
            m3 = fmaxf(m3, leaky(el.w + hr.w));
        }
        for (int o = 32; o > 0; o >>= 1) {
            m0 = fmaxf(m0, __shfl_xor(m0, o));
            m1 = fmaxf(m1, __shfl_xor(m1, o));
            m2 = fmaxf(m2, __shfl_xor(m2, o));
            m3 = fmaxf(m3, __shfl_xor(m3, o));
        }
        // pass B: per-head sum of exp
        float s0 = 0.f, s1 = 0.f, s2 = 0.f, s3 = 0.f;
        for (int k = lane; k < deg; k += 64) {
            float4 el = el_sorted[ofs + k];
            s0 += expf(leaky(el.x + hr.x) - m0);
            s1 += expf(leaky(el.y + hr.y) - m1);
            s2 += expf(leaky(el.z + hr.z) - m2);
            s3 += expf(leaky(el.w + hr.w) - m3);
        }
        for (int o = 32; o > 0; o >>= 1) {
            s0 += __shfl_xor(s0, o);
            s1 += __shfl_xor(s1, o);
            s2 += __shfl_xor(s2, o);
            s3 += __shfl_xor(s3, o);
        }
        float mh = head == 0 ? m0 : head == 1 ? m1 : head == 2 ? m2 : m3;
        float sh = head == 0 ? s0 : head == 1 ? s1 : head == 2 ? s2 : s3;
        float hrh = head == 0 ? hr.x : head == 1 ? hr.y : head == 2 ? hr.z : hr.w;
        float inv_s = 1.f / sh;
        // pass C: serial over edges, all 64 lanes load this edge's h[src] row
        for (int k = 0; k < deg; ++k) {
            int sv = src_sorted[ofs + k];
            float4 el = el_sorted[ofs + k];
            float elh = head == 0 ? el.x : head == 1 ? el.y : head == 2 ? el.z : el.w;
            float alpha = expf(leaky(elh + hrh) - mh) * inv_s;
            const float* hrow = h_ws + (size_t)sv * OUT_DIM + head * HID;
            acc0 += alpha * hrow[d0];
            acc1 += alpha * hrow[d0 + 16];
        }
    }
    // epilogue: out[n, j] = relu(agg[n, h=j&3, d=j>>2] + res[n, j]); lane owns j=lane and j=lane+64
    size_t ob = (size_t)n * OUT_DIM;
    out[ob + lane]      = fmaxf(acc0 + out[ob + lane], 0.f);
    out[ob + 64 + lane] = fmaxf(acc1 + out[ob + 64 + lane], 0.f);
}

extern "C" void kernel_launch(void* const* d_in, const int* in_sizes, int n_in,
                              void* d_out, int out_size, void* d_ws, size_t ws_size,
                              hipStream_t stream) {
    const float* x     = (const float*)d_in[0];
    const int*   ntype = (const int*)d_in[1];
    // d_in[2] = etype (unused by reference)
    const int*   src   = (const int*)d_in[3];
    const int*   dst   = (const int*)d_in[4];
    const float* Wt    = (const float*)d_in[5];
    const float* alw   = (const float*)d_in[6];
    const float* arw   = (const float*)d_in[7];
    const float* Wres  = (const float*)d_in[8];
    const float* bres  = (const float*)d_in[9];
    float* out = (float*)d_out;
    int N = in_sizes[1];
    int E = in_sizes[3];

    char* ws = (char*)d_ws;
    size_t off = 0;
    auto alloc = [&](size_t bytes) -> char* {
        char* p = ws + off;
        off += (bytes + 255) & ~(size_t)255;
        return p;
    };
    float*  h_ws       = (float*)alloc((size_t)N * OUT_DIM * 4);
    float*  hl         = (float*)alloc((size_t)N * NH * 4);
    float*  hr         = (float*)alloc((size_t)N * NH * 4);
    float*  alv        = (float*)alloc(NT * HID * 4);
    float*  arv        = (float*)alloc(NT * HID * 4);
    int*    counts     = (int*)alloc((size_t)N * 4);
    int*    offs       = (int*)alloc((size_t)N * 4);
    int*    cursor     = (int*)alloc((size_t)N * 4);
    int*    bsums      = (int*)alloc(256 * 4);
    int*    src_sorted = (int*)alloc((size_t)E * 4);
    float4* el_sorted  = (float4*)alloc((size_t)E * 16);
    int*    tcnt       = (int*)alloc(NT * 4);
    int*    tstart     = (int*)alloc((NT + 1) * 4);
    int*    tcur       = (int*)alloc(NT * 4);
    int*    pb         = (int*)alloc((NT + 1) * 4);
    int*    order      = (int*)alloc((size_t)N * 4);

    hipMemsetAsync(counts, 0, (size_t)N * 4, stream);
    hipMemsetAsync(cursor, 0, (size_t)N * 4, stream);
    hipMemsetAsync(tcnt, 0, NT * 4, stream);
    hipMemsetAsync(tcur, 0, NT * 4, stream);

    alvec_kernel<<<1, 320, 0, stream>>>(alw, arw, alv, arv);

    int nbs = (N + 255) / 256;

    // node counting sort by type
    type_hist_kernel<<<nbs, 256, 0, stream>>>(ntype, tcnt, N);
    tsetup_kernel<<<1, 1, 0, stream>>>(tcnt, tstart, pb);
    type_scatter_kernel<<<nbs, 256, 0, stream>>>(ntype, tstart, tcur, order, N);

    // typed projection + residual (type-homogeneous blocks)
    int nb1 = (N + BPN - 1) / BPN + NT;   // upper bound on padded block count
    node_proj_typed_kernel<<<nb1, 256, 0, stream>>>(x, order, tstart, tcnt, pb,
                                                    Wt, Wres, bres, h_ws, out);

    hlr_kernel<<<(N * NH + 255) / 256, 256, 0, stream>>>(h_ws, ntype, alv, arv, hl, hr, N);

    hist_kernel<<<(E + 255) / 256, 256, 0, stream>>>(dst, counts, E);

    scan1_kernel<<<nbs, 256, 0, stream>>>(counts, offs, bsums, N);
    scan2_kernel<<<1, 256, 0, stream>>>(bsums, nbs);
    scan3_kernel<<<nbs, 256, 0, stream>>>(offs, bsums, N);

    scatter_kernel<<<(E + 255) / 256, 256, 0, stream>>>(src, dst, offs, cursor,
                                                        (const float4*)hl, src_sorted, el_sorted, E);

    agg_kernel<<<(N + 3) / 4, 256, 0, stream>>>(offs, counts, src_sorted, el_sorted,
                                                (const float4*)hr, h_ws, out, N);
}

// Round 3
// 250.105 us; speedup vs baseline: 1.5549x; 1.3493x over previous
//
#include <hip/hip_runtime.h>
#include <cstdint>
#include <cstddef>

#define IN_DIM 128
#define HID 32
#define NH 4
#define OUT_DIM 128
#define NEG 0.2f
#define NT 5
#define BPN 32   // nodes per block in node_proj_typed

static __device__ __forceinline__ float leaky(float v) { return v > 0.f ? v : NEG * v; }

// ---- fused: al/ar row-sum vectors + type-CSR setup (single block, 320 threads) ----
__global__ void tsetup_alvec_kernel(const float* __restrict__ al_w, const float* __restrict__ ar_w,
                                    float* __restrict__ alvec, float* __restrict__ arvec,
                                    const int* __restrict__ tcnt, int* __restrict__ tstart,
                                    int* __restrict__ pb) {
    int id = threadIdx.x;
    if (id < 2 * NT * HID) {
        int which = id >= NT * HID;
        int r = id - which * NT * HID;          // r = t*32 + i
        const float* srcw = which ? ar_w : al_w;
        int t = r >> 5, i = r & 31;
        const float* p = srcw + (size_t)t * HID * HID + (size_t)i * HID;
        float s = 0.f;
        for (int jj = 0; jj < HID; ++jj) s += p[jj];
        (which ? arvec : alvec)[r] = s;
    }
    if (id == 0) {
        int s = 0, b = 0;
        for (int t = 0; t < NT; ++t) {
            tstart[t] = s;
            pb[t] = b;
            s += tcnt[t];
            b += (tcnt[t] + BPN - 1) / BPN;
        }
        tstart[NT] = s;
        pb[NT] = b;
    }
}

// ---- fused histograms: dst-degree (edge-parallel) + node-type (node-parallel) ----
__global__ void hist_both_kernel(const int* __restrict__ dst, int* __restrict__ counts, int E,
                                 const int* __restrict__ ntype, int* __restrict__ tcnt, int n) {
    __shared__ int lc[NT];
    int tid = threadIdx.x;
    if (tid < NT) lc[tid] = 0;
    __syncthreads();
    int gid = blockIdx.x * 256 + tid;
    if (gid < E) atomicAdd(&counts[dst[gid]], 1);
    if (gid < n) atomicAdd(&lc[ntype[gid]], 1);
    __syncthreads();
    if (tid < NT && lc[tid] > 0) atomicAdd(&tcnt[tid], lc[tid]);
}

__global__ void type_scatter_kernel(const int* __restrict__ ntype, const int* __restrict__ tstart,
                                    int* __restrict__ tcur, int* __restrict__ order, int n) {
    __shared__ int lc[NT];
    __shared__ int gb[NT];
    int tid = threadIdx.x;
    if (tid < NT) lc[tid] = 0;
    __syncthreads();
    int gid = blockIdx.x * 256 + tid;
    int t = -1, rank = 0;
    if (gid < n) {
        t = ntype[gid];
        rank = atomicAdd(&lc[t], 1);
    }
    __syncthreads();
    if (tid < NT && lc[tid] > 0) gb[tid] = atomicAdd(&tcur[tid], lc[tid]);
    __syncthreads();
    if (gid < n) order[tstart[t] + gb[t] + rank] = gid;
}

// K1: typed projection + residual, blocks type-homogeneous via `order`
__global__ void node_proj_typed_kernel(const float* __restrict__ x, const int* __restrict__ order,
                                       const int* __restrict__ tstart, const int* __restrict__ tcnt,
                                       const int* __restrict__ pb,
                                       const float* __restrict__ Wt, const float* __restrict__ Wres,
                                       const float* __restrict__ bres,
                                       float* __restrict__ h_ws, float* __restrict__ out) {
    __shared__ float xs[BPN][IN_DIM];
    __shared__ int nids[BPN];
    __shared__ int spb[NT + 1];
    int tid = threadIdx.x;
    if (tid < NT + 1) spb[tid] = pb[tid];
    __syncthreads();
    int b = blockIdx.x;
    if (b >= spb[NT]) return;
    int t = 0;
    while (b >= spb[t + 1]) ++t;
    int lb = b - spb[t];
    int base = lb * BPN;        // within type t
    int cnt = tcnt[t];
    int ts = tstart[t];
    if (tid < BPN) nids[tid] = (base + tid < cnt) ? order[ts + base + tid] : -1;
    __syncthreads();

    for (int idx = tid; idx < BPN * (IN_DIM / 4); idx += 256) {
        int row = idx >> 5, c4 = idx & 31;
        int n = nids[row];
        float4 v = make_float4(0.f, 0.f, 0.f, 0.f);
        if (n >= 0) v = ((const float4*)(x + (size_t)n * IN_DIM))[c4];
        ((float4*)xs[row])[c4] = v;
    }
    __syncthreads();

    int wslot = tid >> 6, lane = tid & 63;
    const float* wtp = Wt + (size_t)t * IN_DIM * OUT_DIM;

    float at0[8], at1[8], ar0[8], ar1[8];
#pragma unroll
    for (int k = 0; k < 8; ++k) { at0[k] = at1[k] = ar0[k] = ar1[k] = 0.f; }

    for (int i = 0; i < IN_DIM; ++i) {
        float wt0 = wtp[(size_t)i * OUT_DIM + lane];
        float wt1 = wtp[(size_t)i * OUT_DIM + lane + 64];
        float wr0 = Wres[(size_t)i * OUT_DIM + lane];
        float wr1 = Wres[(size_t)i * OUT_DIM + lane + 64];
#pragma unroll
        for (int k = 0; k < 8; ++k) {
            float xv = xs[wslot * 8 + k][i];
            at0[k] += xv * wt0;
            at1[k] += xv * wt1;
            ar0[k] += xv * wr0;
            ar1[k] += xv * wr1;
        }
    }

    float b0 = bres[lane], b1 = bres[lane + 64];
#pragma unroll
    for (int k = 0; k < 8; ++k) {
        int n = nids[wslot * 8 + k];
        if (n < 0) continue;
        size_t ob = (size_t)n * OUT_DIM;
        h_ws[ob + lane]      = at0[k];
        h_ws[ob + lane + 64] = at1[k];
        out[ob + lane]       = ar0[k] + b0;
        out[ob + lane + 64]  = ar1[k] + b1;
    }
}

// K2: hl[n*4+h] = h[n,h,:]·alvec[t],  hr likewise
__global__ void hlr_kernel(const float* __restrict__ h_ws, const int* __restrict__ ntype,
                           const float* __restrict__ alvec, const float* __restrict__ arvec,
                           float* __restrict__ hl, float* __restrict__ hr, int n_nodes) {
    int id = blockIdx.x * 256 + threadIdx.x;
    if (id >= n_nodes * NH) return;
    int n = id >> 2, h = id & 3;
    int t = ntype[n];
    const float4* hp = (const float4*)(h_ws + (size_t)n * OUT_DIM + h * HID);
    const float4* av = (const float4*)(alvec + t * HID);
    const float4* bv = (const float4*)(arvec + t * HID);
    float sl = 0.f, sr = 0.f;
#pragma unroll
    for (int i = 0; i < HID / 4; ++i) {
        float4 v = hp[i], a = av[i], b = bv[i];
        sl += v.x * a.x + v.y * a.y + v.z * a.z + v.w * a.w;
        sr += v.x * b.x + v.y * b.y + v.z * b.z + v.w * b.w;
    }
    hl[id] = sl;
    hr[id] = sr;
}

// K4a: per-block exclusive scan + block sums
__global__ void scan1_kernel(const int* __restrict__ counts, int* __restrict__ offs,
                             int* __restrict__ bsums, int n) {
    __shared__ int tmp[256];
    int tid = threadIdx.x, gid = blockIdx.x * 256 + tid;
    int v = (gid < n) ? counts[gid] : 0;
    tmp[tid] = v;
    __syncthreads();
    for (int o = 1; o < 256; o <<= 1) {
        int add = (tid >= o) ? tmp[tid - o] : 0;
        __syncthreads();
        tmp[tid] += add;
        __syncthreads();
    }
    if (gid < n) offs[gid] = tmp[tid] - v;   // exclusive
    if (tid == 255) bsums[blockIdx.x] = tmp[255];
}

// K4b: single-block exclusive scan of block sums (nb <= 256)
__global__ void scan2_kernel(int* __restrict__ bsums, int nb) {
    __shared__ int tmp[256];
    int tid = threadIdx.x;
    int v = (tid < nb) ? bsums[tid] : 0;
    tmp[tid] = v;
    __syncthreads();
    for (int o = 1; o < 256; o <<= 1) {
        int add = (tid >= o) ? tmp[tid - o] : 0;
        __syncthreads();
        tmp[tid] += add;
        __syncthreads();
    }
    if (tid < nb) bsums[tid] = tmp[tid] - v;
}

// K4c: add block offsets back
__global__ void scan3_kernel(int* __restrict__ offs, const int* __restrict__ bsums, int n) {
    int gid = blockIdx.x * 256 + threadIdx.x;
    if (gid < n) offs[gid] += bsums[blockIdx.x];
}

// K5: scatter edges into CSR-by-dst; pre-gather hl[src] per edge
__global__ void scatter_kernel(const int* __restrict__ src, const int* __restrict__ dst,
                               const int* __restrict__ offs, int* __restrict__ cursor,
                               const float4* __restrict__ hl4, int* __restrict__ src_sorted,
                               float4* __restrict__ el_sorted, int E) {
    int e = blockIdx.x * 256 + threadIdx.x;
    if (e >= E) return;
    int d = dst[e];
    int pos = offs[d] + atomicAdd(&cursor[d], 1);
    int sv = src[e];
    src_sorted[pos] = sv;
    el_sorted[pos] = hl4[sv];
}

// K6 v2: 16 lanes per node (4 nodes per wave).
// Lane l owns h_ws dwords l*8..l*8+7 of the source row -> all one head (l>>2),
// so one alpha per lane per edge and two float4 gathers per edge.
__global__ void agg_kernel(const int* __restrict__ offs, const int* __restrict__ counts,
                           const int* __restrict__ src_sorted, const float4* __restrict__ el4,
                           const float4* __restrict__ hr4, const float4* __restrict__ h_ws4,
                           float* __restrict__ out, int n_nodes) {
    int gid = blockIdx.x * 256 + threadIdx.x;
    int n = gid >> 4;
    if (n >= n_nodes) return;
    int l = threadIdx.x & 15;
    int myh = l >> 2;
    int ofs = offs[n], deg = counts[n];
    float acc[8];
#pragma unroll
    for (int m = 0; m < 8; ++m) acc[m] = 0.f;

    if (deg > 0) {
        float4 hv = hr4[n];
        // pass A: per-head max over edges (lane strides by 16)
        float m0 = -3e38f, m1 = -3e38f, m2 = -3e38f, m3 = -3e38f;
        for (int k = l; k < deg; k += 16) {
            float4 el = el4[ofs + k];
            m0 = fmaxf(m0, leaky(el.x + hv.x));
            m1 = fmaxf(m1, leaky(el.y + hv.y));
            m2 = fmaxf(m2, leaky(el.z + hv.z));
            m3 = fmaxf(m3, leaky(el.w + hv.w));
        }
#pragma unroll
        for (int o = 1; o < 16; o <<= 1) {
            m0 = fmaxf(m0, __shfl_xor(m0, o));
            m1 = fmaxf(m1, __shfl_xor(m1, o));
            m2 = fmaxf(m2, __shfl_xor(m2, o));
            m3 = fmaxf(m3, __shfl_xor(m3, o));
        }
        // pass B: per-head sum of exp
        float s0 = 0.f, s1 = 0.f, s2 = 0.f, s3 = 0.f;
        for (int k = l; k < deg; k += 16) {
            float4 el = el4[ofs + k];
            s0 += __expf(leaky(el.x + hv.x) - m0);
            s1 += __expf(leaky(el.y + hv.y) - m1);
            s2 += __expf(leaky(el.z + hv.z) - m2);
            s3 += __expf(leaky(el.w + hv.w) - m3);
        }
#pragma unroll
        for (int o = 1; o < 16; o <<= 1) {
            s0 += __shfl_xor(s0, o);
            s1 += __shfl_xor(s1, o);
            s2 += __shfl_xor(s2, o);
            s3 += __shfl_xor(s3, o);
        }
        float mh  = myh < 2 ? (myh == 0 ? m0 : m1) : (myh == 2 ? m2 : m3);
        float sh  = myh < 2 ? (myh == 0 ? s0 : s1) : (myh == 2 ? s2 : s3);
        float hrh = myh < 2 ? (myh == 0 ? hv.x : hv.y) : (myh == 2 ? hv.z : hv.w);
        float inv_s = 1.f / sh;

        const float* elf = (const float*)el4;
        int fidx = l << 1;                       // lane's float4 index within a 32-float4 row
        int k = 0;
        for (; k + 2 <= deg; k += 2) {
            int sv0 = src_sorted[ofs + k];
            int sv1 = src_sorted[ofs + k + 1];
            float e0 = elf[(size_t)(ofs + k) * 4 + myh];
            float e1 = elf[(size_t)(ofs + k + 1) * 4 + myh];
            float4 u0 = h_ws4[(size_t)sv0 * 32 + fidx];
            float4 v0 = h_ws4[(size_t)sv0 * 32 + fidx + 1];
            float4 u1 = h_ws4[(size_t)sv1 * 32 + fidx];
            float4 v1 = h_ws4[(size_t)sv1 * 32 + fidx + 1];
            float a0 = __expf(leaky(e0 + hrh) - mh) * inv_s;
            float a1 = __expf(leaky(e1 + hrh) - mh) * inv_s;
            acc[0] += a0 * u0.x; acc[1] += a0 * u0.y; acc[2] += a0 * u0.z; acc[3] += a0 * u0.w;
            acc[4] += a0 * v0.x; acc[5] += a0 * v0.y; acc[6] += a0 * v0.z; acc[7] += a0 * v0.w;
            acc[0] += a1 * u1.x; acc[1] += a1 * u1.y; acc[2] += a1 * u1.z; acc[3] += a1 * u1.w;
            acc[4] += a1 * v1.x; acc[5] += a1 * v1.y; acc[6] += a1 * v1.z; acc[7] += a1 * v1.w;
        }
        if (k < deg) {
            int sv0 = src_sorted[ofs + k];
            float e0 = elf[(size_t)(ofs + k) * 4 + myh];
            float4 u0 = h_ws4[(size_t)sv0 * 32 + fidx];
            float4 v0 = h_ws4[(size_t)sv0 * 32 + fidx + 1];
            float a0 = __expf(leaky(e0 + hrh) - mh) * inv_s;
            acc[0] += a0 * u0.x; acc[1] += a0 * u0.y; acc[2] += a0 * u0.z; acc[3] += a0 * u0.w;
            acc[4] += a0 * v0.x; acc[5] += a0 * v0.y; acc[6] += a0 * v0.z; acc[7] += a0 * v0.w;
        }
    }
    // epilogue: h_ws dword i = l*8+m -> (h = l>>2, d = (l&3)*8+m) -> out col j = d*4+h
    size_t ob = (size_t)n * OUT_DIM;
    int based = (l & 3) << 3;
#pragma unroll
    for (int m = 0; m < 8; ++m) {
        int j = ((based + m) << 2) | myh;
        out[ob + j] = fmaxf(acc[m] + out[ob + j], 0.f);
    }
}

extern "C" void kernel_launch(void* const* d_in, const int* in_sizes, int n_in,
                              void* d_out, int out_size, void* d_ws, size_t ws_size,
                              hipStream_t stream) {
    const float* x     = (const float*)d_in[0];
    const int*   ntype = (const int*)d_in[1];
    // d_in[2] = etype (unused by reference)
    const int*   src   = (const int*)d_in[3];
    const int*   dst   = (const int*)d_in[4];
    const float* Wt    = (const float*)d_in[5];
    const float* alw   = (const float*)d_in[6];
    const float* arw   = (const float*)d_in[7];
    const float* Wres  = (const float*)d_in[8];
    const float* bres  = (const float*)d_in[9];
    float* out = (float*)d_out;
    int N = in_sizes[1];
    int E = in_sizes[3];

    char* ws = (char*)d_ws;
    size_t off = 0;
    auto alloc = [&](size_t bytes) -> char* {
        char* p = ws + off;
        off += (bytes + 255) & ~(size_t)255;
        return p;
    };
    float*  h_ws       = (float*)alloc((size_t)N * OUT_DIM * 4);
    float*  hl         = (float*)alloc((size_t)N * NH * 4);
    float*  hr         = (float*)alloc((size_t)N * NH * 4);
    float*  alv        = (float*)alloc(NT * HID * 4);
    float*  arv        = (float*)alloc(NT * HID * 4);
    int*    offs       = (int*)alloc((size_t)N * 4);
    int*    bsums      = (int*)alloc(256 * 4);
    int*    src_sorted = (int*)alloc((size_t)E * 4);
    float4* el_sorted  = (float4*)alloc((size_t)E * 16);
    int*    tstart     = (int*)alloc((NT + 1) * 4);
    int*    pb         = (int*)alloc((NT + 1) * 4);
    int*    order      = (int*)alloc((size_t)N * 4);
    // zero-initialized group (single memset)
    char*   zstart     = ws + off;
    int*    counts     = (int*)alloc((size_t)N * 4);
    int*    cursor     = (int*)alloc((size_t)N * 4);
    int*    tcnt       = (int*)alloc(NT * 4);
    int*    tcur       = (int*)alloc(NT * 4);
    size_t  zlen       = (ws + off) - zstart;

    hipMemsetAsync(zstart, 0, zlen, stream);

    int nbs = (N + 255) / 256;
    int nbe = (E + 255) / 256;

    hist_both_kernel<<<nbe, 256, 0, stream>>>(dst, counts, E, ntype, tcnt, N);
    tsetup_alvec_kernel<<<1, 320, 0, stream>>>(alw, arw, alv, arv, tcnt, tstart, pb);
    type_scatter_kernel<<<nbs, 256, 0, stream>>>(ntype, tstart, tcur, order, N);

    int nb1 = (N + BPN - 1) / BPN + NT;   // upper bound on padded block count
    node_proj_typed_kernel<<<nb1, 256, 0, stream>>>(x, order, tstart, tcnt, pb,
                                                    Wt, Wres, bres, h_ws, out);

    hlr_kernel<<<(N * NH + 255) / 256, 256, 0, stream>>>(h_ws, ntype, alv, arv, hl, hr, N);

    scan1_kernel<<<nbs, 256, 0, stream>>>(counts, offs, bsums, N);
    scan2_kernel<<<1, 256, 0, stream>>>(bsums, nbs);
    scan3_kernel<<<nbs, 256, 0, stream>>>(offs, bsums, N);

    scatter_kernel<<<nbe, 256, 0, stream>>>(src, dst, offs, cursor,
                                            (const float4*)hl, src_sorted, el_sorted, E);

    agg_kernel<<<(N * 16 + 255) / 256, 256, 0, stream>>>(offs, counts, src_sorted,
                                                         (const float4*)el_sorted,
                                                         (const float4*)hr,
                                                         (const float4*)h_ws, out, N);
}

// Round 4
// 224.337 us; speedup vs baseline: 1.7335x; 1.1149x over previous
//
#include <hip/hip_runtime.h>
#include <cstdint>
#include <cstddef>

#define IN_DIM 128
#define HID 32
#define NH 4
#define OUT_DIM 128
#define NEG 0.2f
#define NT 5
#define BPN 32        // nodes per block in node_proj
#define NCOLS 272     // 128 typed | 128 res | 4 hl | 4 hr | 8 pad  (17 tiles of 16)

typedef __attribute__((ext_vector_type(8))) __bf16 bf16x8;
typedef __attribute__((ext_vector_type(4))) float f32x4;

static __device__ __forceinline__ float leaky(float v) { return v > 0.f ? v : NEG * v; }
static __device__ __forceinline__ float blo(unsigned u) { return __uint_as_float(u << 16); }
static __device__ __forceinline__ float bhi(unsigned u) { return __uint_as_float(u & 0xffff0000u); }

// ---- fused histograms: dst-degree (edge-parallel) + node-type (node-parallel) ----
__global__ void hist_both_kernel(const int* __restrict__ dst, int* __restrict__ counts, int E,
                                 const int* __restrict__ ntype, int* __restrict__ tcnt, int n) {
    __shared__ int lc[NT];
    int tid = threadIdx.x;
    if (tid < NT) lc[tid] = 0;
    __syncthreads();
    int gid = blockIdx.x * 256 + tid;
    if (gid < E) atomicAdd(&counts[dst[gid]], 1);
    if (gid < n) atomicAdd(&lc[ntype[gid]], 1);
    __syncthreads();
    if (tid < NT && lc[tid] > 0) atomicAdd(&tcnt[tid], lc[tid]);
}

// ---- prep: build Wcat (bf16 hi/lo, transposed [t][n][k]) + type-CSR setup ----
// Wcat cols: n<128 -> W_typed[t][k][n]; 128..255 -> W_res[k][n-128];
// 256..259 -> sum_i Wt[t][k][h*32+i]*alv[t][i] (h=n-256); 260..263 same w/ arv; else 0.
__global__ void prep_kernel(const float* __restrict__ Wt, const float* __restrict__ Wres,
                            const float* __restrict__ alw, const float* __restrict__ arw,
                            const int* __restrict__ tcnt, int* __restrict__ tstart,
                            int* __restrict__ pb,
                            __bf16* __restrict__ Whi, __bf16* __restrict__ Wlo) {
    int t = blockIdx.x;
    int tid = threadIdx.x;
    __shared__ float alv[HID], arv[HID];
    if (tid < 64) {
        int which = tid >= HID;
        int i = tid & (HID - 1);
        const float* p = (which ? arw : alw) + ((size_t)t * HID + i) * HID;
        float s = 0.f;
        for (int j = 0; j < HID; ++j) s += p[j];
        (which ? arv : alv)[i] = s;
    }
    if (t == 0 && tid == 255) {
        int s = 0, b = 0;
        for (int tt = 0; tt < NT; ++tt) {
            tstart[tt] = s;
            pb[tt] = b;
            s += tcnt[tt];
            b += (tcnt[tt] + BPN - 1) / BPN;
        }
        tstart[NT] = s;
        pb[NT] = b;
    }
    __syncthreads();
    for (int idx = tid; idx < NCOLS * IN_DIM; idx += 256) {
        int n = idx >> 7, k = idx & 127;
        float w;
        if (n < 128) {
            w = Wt[((size_t)t * IN_DIM + k) * OUT_DIM + n];
        } else if (n < 256) {
            w = Wres[(size_t)k * OUT_DIM + (n - 128)];
        } else if (n < 264) {
            int h = (n - 256) & 3;
            const float* av = (n >= 260) ? arv : alv;
            float s = 0.f;
            for (int i = 0; i < HID; ++i)
                s += Wt[((size_t)t * IN_DIM + k) * OUT_DIM + h * HID + i] * av[i];
            w = s;
        } else {
            w = 0.f;
        }
        __bf16 hi = (__bf16)w;
        __bf16 lo = (__bf16)(w - (float)hi);
        size_t o = ((size_t)t * NCOLS + n) * IN_DIM + k;
        Whi[o] = hi;
        Wlo[o] = lo;
    }
}

__global__ void type_scatter_kernel(const int* __restrict__ ntype, const int* __restrict__ tstart,
                                    int* __restrict__ tcur, int* __restrict__ order, int n) {
    __shared__ int lc[NT];
    __shared__ int gb[NT];
    int tid = threadIdx.x;
    if (tid < NT) lc[tid] = 0;
    __syncthreads();
    int gid = blockIdx.x * 256 + tid;
    int t = -1, rank = 0;
    if (gid < n) {
        t = ntype[gid];
        rank = atomicAdd(&lc[t], 1);
    }
    __syncthreads();
    if (tid < NT && lc[tid] > 0) gb[tid] = atomicAdd(&tcur[tid], lc[tid]);
    __syncthreads();
    if (gid < n) order[tstart[t] + gb[t] + rank] = gid;
}

// ---- node projection via split-bf16 MFMA ----
// Block: 32 nodes (one type), 256 threads = 4 waves. Wave w owns cols w*64..w*64+63;
// wave 3 also owns tile 16 (cols 256..271, the hl/hr columns).
// mfma_f32_16x16x32_bf16: A row=lane&15, k=(lane>>4)*8+j; D col=lane&15, row=(lane>>4)*4+reg.
__global__ void __launch_bounds__(256) node_proj_mfma_kernel(
        const float* __restrict__ x, const int* __restrict__ order,
        const int* __restrict__ tstart, const int* __restrict__ tcnt,
        const int* __restrict__ pb,
        const __bf16* __restrict__ Whi, const __bf16* __restrict__ Wlo,
        const float* __restrict__ bres,
        __bf16* __restrict__ h_bf, float* __restrict__ hl, float* __restrict__ hr,
        float* __restrict__ out) {
    __shared__ __bf16 xs_hi[BPN][IN_DIM + 8];
    __shared__ __bf16 xs_lo[BPN][IN_DIM + 8];
    __shared__ int nids[BPN];
    __shared__ int spb[NT + 1];
    int tid = threadIdx.x;
    if (tid < NT + 1) spb[tid] = pb[tid];
    __syncthreads();
    int b = blockIdx.x;
    if (b >= spb[NT]) return;
    int t = 0;
    while (b >= spb[t + 1]) ++t;
    int base = (b - spb[t]) * BPN;
    int cnt = tcnt[t], ts = tstart[t];
    if (tid < BPN) nids[tid] = (base + tid < cnt) ? order[ts + base + tid] : -1;
    __syncthreads();

    for (int idx = tid; idx < BPN * (IN_DIM / 4); idx += 256) {
        int row = idx >> 5, c4 = idx & 31;
        int n = nids[row];
        float4 v = make_float4(0.f, 0.f, 0.f, 0.f);
        if (n >= 0) v = ((const float4*)(x + (size_t)n * IN_DIM))[c4];
        __bf16 h0 = (__bf16)v.x, h1 = (__bf16)v.y, h2 = (__bf16)v.z, h3 = (__bf16)v.w;
        xs_hi[row][c4 * 4 + 0] = h0;
        xs_hi[row][c4 * 4 + 1] = h1;
        xs_hi[row][c4 * 4 + 2] = h2;
        xs_hi[row][c4 * 4 + 3] = h3;
        xs_lo[row][c4 * 4 + 0] = (__bf16)(v.x - (float)h0);
        xs_lo[row][c4 * 4 + 1] = (__bf16)(v.y - (float)h1);
        xs_lo[row][c4 * 4 + 2] = (__bf16)(v.z - (float)h2);
        xs_lo[row][c4 * 4 + 3] = (__bf16)(v.w - (float)h3);
    }
    __syncthreads();

    int w = tid >> 6, lane = tid & 63;
    int lr = lane & 15, lg = lane >> 4;
    bool w3 = (w == 3);

    f32x4 acc[2][5];
#pragma unroll
    for (int m = 0; m < 2; ++m)
#pragma unroll
        for (int nt = 0; nt < 5; ++nt) acc[m][nt] = (f32x4)0.f;

    const __bf16* Wbh = Whi + (size_t)t * NCOLS * IN_DIM;
    const __bf16* Wbl = Wlo + (size_t)t * NCOLS * IN_DIM;

#pragma unroll
    for (int ks = 0; ks < 4; ++ks) {
        int kb = ks * 32 + lg * 8;
        bf16x8 ah0 = *(const bf16x8*)&xs_hi[lr][kb];
        bf16x8 ah1 = *(const bf16x8*)&xs_hi[16 + lr][kb];
        bf16x8 al0 = *(const bf16x8*)&xs_lo[lr][kb];
        bf16x8 al1 = *(const bf16x8*)&xs_lo[16 + lr][kb];
#pragma unroll
        for (int nt = 0; nt < 5; ++nt) {
            if (nt == 4 && !w3) continue;
            int ng = (nt < 4) ? (w * 4 + nt) : 16;
            size_t wo = (size_t)(ng * 16 + lr) * IN_DIM + kb;
            bf16x8 bh = *(const bf16x8*)(Wbh + wo);
            bf16x8 bl = *(const bf16x8*)(Wbl + wo);
            acc[0][nt] = __builtin_amdgcn_mfma_f32_16x16x32_bf16(ah0, bh, acc[0][nt], 0, 0, 0);
            acc[0][nt] = __builtin_amdgcn_mfma_f32_16x16x32_bf16(ah0, bl, acc[0][nt], 0, 0, 0);
            acc[0][nt] = __builtin_amdgcn_mfma_f32_16x16x32_bf16(al0, bh, acc[0][nt], 0, 0, 0);
            acc[1][nt] = __builtin_amdgcn_mfma_f32_16x16x32_bf16(ah1, bh, acc[1][nt], 0, 0, 0);
            acc[1][nt] = __builtin_amdgcn_mfma_f32_16x16x32_bf16(ah1, bl, acc[1][nt], 0, 0, 0);
            acc[1][nt] = __builtin_amdgcn_mfma_f32_16x16x32_bf16(al1, bh, acc[1][nt], 0, 0, 0);
        }
    }

#pragma unroll
    for (int nt = 0; nt < 5; ++nt) {
        if (nt == 4 && !w3) continue;
        int ng = (nt < 4) ? (w * 4 + nt) : 16;
        int col = ng * 16 + lr;
        float bb = (col >= 128 && col < 256) ? bres[col - 128] : 0.f;
#pragma unroll
        for (int m = 0; m < 2; ++m) {
#pragma unroll
            for (int r = 0; r < 4; ++r) {
                int brow = m * 16 + lg * 4 + r;
                int nid = nids[brow];
                if (nid < 0) continue;
                float v = acc[m][nt][r];
                if (col < 128) {
                    h_bf[(size_t)nid * OUT_DIM + col] = (__bf16)v;
                } else if (col < 256) {
                    out[(size_t)nid * OUT_DIM + (col - 128)] = v + bb;
                } else if (col < 260) {
                    hl[nid * NH + (col - 256)] = v;
                } else if (col < 264) {
                    hr[nid * NH + (col - 260)] = v;
                }
            }
        }
    }
}

// ---- scans ----
__global__ void scan1_kernel(const int* __restrict__ counts, int* __restrict__ offs,
                             int* __restrict__ bsums, int n) {
    __shared__ int tmp[256];
    int tid = threadIdx.x, gid = blockIdx.x * 256 + tid;
    int v = (gid < n) ? counts[gid] : 0;
    tmp[tid] = v;
    __syncthreads();
    for (int o = 1; o < 256; o <<= 1) {
        int add = (tid >= o) ? tmp[tid - o] : 0;
        __syncthreads();
        tmp[tid] += add;
        __syncthreads();
    }
    if (gid < n) offs[gid] = tmp[tid] - v;
    if (tid == 255) bsums[blockIdx.x] = tmp[255];
}

__global__ void scan2_kernel(int* __restrict__ bsums, int nb) {
    __shared__ int tmp[256];
    int tid = threadIdx.x;
    int v = (tid < nb) ? bsums[tid] : 0;
    tmp[tid] = v;
    __syncthreads();
    for (int o = 1; o < 256; o <<= 1) {
        int add = (tid >= o) ? tmp[tid - o] : 0;
        __syncthreads();
        tmp[tid] += add;
        __syncthreads();
    }
    if (tid < nb) bsums[tid] = tmp[tid] - v;
}

__global__ void scan3_kernel(int* __restrict__ offs, const int* __restrict__ bsums, int n) {
    int gid = blockIdx.x * 256 + threadIdx.x;
    if (gid < n) offs[gid] += bsums[blockIdx.x];
}

// ---- scatter edges into CSR-by-dst; pre-gather hl[src] ----
__global__ void scatter_kernel(const int* __restrict__ src, const int* __restrict__ dst,
                               const int* __restrict__ offs, int* __restrict__ cursor,
                               const float4* __restrict__ hl4, int* __restrict__ src_sorted,
                               float4* __restrict__ el_sorted, int E) {
    int e = blockIdx.x * 256 + threadIdx.x;
    if (e >= E) return;
    int d = dst[e];
    int pos = offs[d] + atomicAdd(&cursor[d], 1);
    int sv = src[e];
    src_sorted[pos] = sv;
    el_sorted[pos] = hl4[sv];
}

// ---- agg: 16 lanes per node; bf16 h gathers ----
__global__ void agg_kernel(const int* __restrict__ offs, const int* __restrict__ counts,
                           const int* __restrict__ src_sorted, const float4* __restrict__ el4,
                           const float4* __restrict__ hr4, const __bf16* __restrict__ h_bf,
                           float* __restrict__ out, int n_nodes) {
    int gid = blockIdx.x * 256 + threadIdx.x;
    int n = gid >> 4;
    if (n >= n_nodes) return;
    int l = threadIdx.x & 15;
    int myh = l >> 2;
    int ofs = offs[n], deg = counts[n];
    float acc[8];
#pragma unroll
    for (int m = 0; m < 8; ++m) acc[m] = 0.f;

    if (deg > 0) {
        float4 hv = hr4[n];
        float m0 = -3e38f, m1 = -3e38f, m2 = -3e38f, m3 = -3e38f;
        for (int k = l; k < deg; k += 16) {
            float4 el = el4[ofs + k];
            m0 = fmaxf(m0, leaky(el.x + hv.x));
            m1 = fmaxf(m1, leaky(el.y + hv.y));
            m2 = fmaxf(m2, leaky(el.z + hv.z));
            m3 = fmaxf(m3, leaky(el.w + hv.w));
        }
#pragma unroll
        for (int o = 1; o < 16; o <<= 1) {
            m0 = fmaxf(m0, __shfl_xor(m0, o));
            m1 = fmaxf(m1, __shfl_xor(m1, o));
            m2 = fmaxf(m2, __shfl_xor(m2, o));
            m3 = fmaxf(m3, __shfl_xor(m3, o));
        }
        float s0 = 0.f, s1 = 0.f, s2 = 0.f, s3 = 0.f;
        for (int k = l; k < deg; k += 16) {
            float4 el = el4[ofs + k];
            s0 += __expf(leaky(el.x + hv.x) - m0);
            s1 += __expf(leaky(el.y + hv.y) - m1);
            s2 += __expf(leaky(el.z + hv.z) - m2);
            s3 += __expf(leaky(el.w + hv.w) - m3);
        }
#pragma unroll
        for (int o = 1; o < 16; o <<= 1) {
            s0 += __shfl_xor(s0, o);
            s1 += __shfl_xor(s1, o);
            s2 += __shfl_xor(s2, o);
            s3 += __shfl_xor(s3, o);
        }
        float mh  = myh < 2 ? (myh == 0 ? m0 : m1) : (myh == 2 ? m2 : m3);
        float sh  = myh < 2 ? (myh == 0 ? s0 : s1) : (myh == 2 ? s2 : s3);
        float hrh = myh < 2 ? (myh == 0 ? hv.x : hv.y) : (myh == 2 ? hv.z : hv.w);
        float inv_s = 1.f / sh;

        const float* elf = (const float*)el4;
        int k = 0;
        for (; k + 2 <= deg; k += 2) {
            int sv0 = src_sorted[ofs + k];
            int sv1 = src_sorted[ofs + k + 1];
            float e0 = elf[(size_t)(ofs + k) * 4 + myh];
            float e1 = elf[(size_t)(ofs + k + 1) * 4 + myh];
            uint4 u0 = *(const uint4*)(h_bf + (size_t)sv0 * OUT_DIM + l * 8);
            uint4 u1 = *(const uint4*)(h_bf + (size_t)sv1 * OUT_DIM + l * 8);
            float a0 = __expf(leaky(e0 + hrh) - mh) * inv_s;
            float a1 = __expf(leaky(e1 + hrh) - mh) * inv_s;
            acc[0] += a0 * blo(u0.x); acc[1] += a0 * bhi(u0.x);
            acc[2] += a0 * blo(u0.y); acc[3] += a0 * bhi(u0.y);
            acc[4] += a0 * blo(u0.z); acc[5] += a0 * bhi(u0.z);
            acc[6] += a0 * blo(u0.w); acc[7] += a0 * bhi(u0.w);
            acc[0] += a1 * blo(u1.x); acc[1] += a1 * bhi(u1.x);
            acc[2] += a1 * blo(u1.y); acc[3] += a1 * bhi(u1.y);
            acc[4] += a1 * blo(u1.z); acc[5] += a1 * bhi(u1.z);
            acc[6] += a1 * blo(u1.w); acc[7] += a1 * bhi(u1.w);
        }
        if (k < deg) {
            int sv0 = src_sorted[ofs + k];
            float e0 = elf[(size_t)(ofs + k) * 4 + myh];
            uint4 u0 = *(const uint4*)(h_bf + (size_t)sv0 * OUT_DIM + l * 8);
            float a0 = __expf(leaky(e0 + hrh) - mh) * inv_s;
            acc[0] += a0 * blo(u0.x); acc[1] += a0 * bhi(u0.x);
            acc[2] += a0 * blo(u0.y); acc[3] += a0 * bhi(u0.y);
            acc[4] += a0 * blo(u0.z); acc[5] += a0 * bhi(u0.z);
            acc[6] += a0 * blo(u0.w); acc[7] += a0 * bhi(u0.w);
        }
    }
    // h dword i = l*8+m -> (head = l>>2, d = (l&3)*8+m) -> out col j = d*4+head
    size_t ob = (size_t)n * OUT_DIM;
    int based = (l & 3) << 3;
#pragma unroll
    for (int m = 0; m < 8; ++m) {
        int j = ((based + m) << 2) | myh;
        out[ob + j] = fmaxf(acc[m] + out[ob + j], 0.f);
    }
}

extern "C" void kernel_launch(void* const* d_in, const int* in_sizes, int n_in,
                              void* d_out, int out_size, void* d_ws, size_t ws_size,
                              hipStream_t stream) {
    const float* x     = (const float*)d_in[0];
    const int*   ntype = (const int*)d_in[1];
    const int*   src   = (const int*)d_in[3];
    const int*   dst   = (const int*)d_in[4];
    const float* Wt    = (const float*)d_in[5];
    const float* alw   = (const float*)d_in[6];
    const float* arw   = (const float*)d_in[7];
    const float* Wres  = (const float*)d_in[8];
    const float* bres  = (const float*)d_in[9];
    float* out = (float*)d_out;
    int N = in_sizes[1];
    int E = in_sizes[3];

    char* ws = (char*)d_ws;
    size_t off = 0;
    auto alloc = [&](size_t bytes) -> char* {
        char* p = ws + off;
        off += (bytes + 255) & ~(size_t)255;
        return p;
    };
    __bf16* h_bf       = (__bf16*)alloc((size_t)N * OUT_DIM * 2);
    float*  hl         = (float*)alloc((size_t)N * NH * 4);
    float*  hr         = (float*)alloc((size_t)N * NH * 4);
    int*    offs       = (int*)alloc((size_t)N * 4);
    int*    bsums      = (int*)alloc(256 * 4);
    int*    src_sorted = (int*)alloc((size_t)E * 4);
    float4* el_sorted  = (float4*)alloc((size_t)E * 16);
    int*    tstart     = (int*)alloc((NT + 1) * 4);
    int*    pb         = (int*)alloc((NT + 1) * 4);
    int*    order      = (int*)alloc((size_t)N * 4);
    __bf16* Whi        = (__bf16*)alloc((size_t)NT * NCOLS * IN_DIM * 2);
    __bf16* Wlo        = (__bf16*)alloc((size_t)NT * NCOLS * IN_DIM * 2);
    // zero-initialized group (single memset)
    char*   zstart     = ws + off;
    int*    counts     = (int*)alloc((size_t)N * 4);
    int*    cursor     = (int*)alloc((size_t)N * 4);
    int*    tcnt       = (int*)alloc(NT * 4);
    int*    tcur       = (int*)alloc(NT * 4);
    size_t  zlen       = (ws + off) - zstart;

    hipMemsetAsync(zstart, 0, zlen, stream);

    int nbs = (N + 255) / 256;
    int nbe = (E + 255) / 256;

    hist_both_kernel<<<nbe, 256, 0, stream>>>(dst, counts, E, ntype, tcnt, N);
    prep_kernel<<<NT, 256, 0, stream>>>(Wt, Wres, alw, arw, tcnt, tstart, pb, Whi, Wlo);
    type_scatter_kernel<<<nbs, 256, 0, stream>>>(ntype, tstart, tcur, order, N);

    int nb1 = (N + BPN - 1) / BPN + NT;
    node_proj_mfma_kernel<<<nb1, 256, 0, stream>>>(x, order, tstart, tcnt, pb,
                                                   Whi, Wlo, bres, h_bf, hl, hr, out);

    scan1_kernel<<<nbs, 256, 0, stream>>>(counts, offs, bsums, N);
    scan2_kernel<<<1, 256, 0, stream>>>(bsums, nbs);
    scan3_kernel<<<nbs, 256, 0, stream>>>(offs, bsums, N);

    scatter_kernel<<<nbe, 256, 0, stream>>>(src, dst, offs, cursor,
                                            (const float4*)hl, src_sorted, el_sorted, E);

    agg_kernel<<<(N * 16 + 255) / 256, 256, 0, stream>>>(offs, counts, src_sorted,
                                                         (const float4*)el_sorted,
                                                         (const float4*)hr, h_bf, out, N);
}

// Round 5
// 220.591 us; speedup vs baseline: 1.7629x; 1.0170x over previous
//
#include <hip/hip_runtime.h>
#include <cstdint>
#include <cstddef>

#define IN_DIM 128
#define HID 32
#define NH 4
#define OUT_DIM 128
#define NEG 0.2f
#define NT 5
#define BPN 64        // nodes per block in node_proj
#define NCOLS 272     // 128 typed | 128 res | 4 hl | 4 hr | 8 pad  (17 tiles of 16)
#define XPAD 8        // xs row pad (keeps 16B alignment)

typedef __attribute__((ext_vector_type(8))) __bf16 bf16x8;
typedef __attribute__((ext_vector_type(4))) float f32x4;

static __device__ __forceinline__ float leaky(float v) { return v > 0.f ? v : NEG * v; }
static __device__ __forceinline__ float blo(unsigned u) { return __uint_as_float(u << 16); }
static __device__ __forceinline__ float bhi(unsigned u) { return __uint_as_float(u & 0xffff0000u); }

// ---- fused histograms: dst-degree (edge-parallel) + node-type (node-parallel) ----
__global__ void hist_both_kernel(const int* __restrict__ dst, int* __restrict__ counts, int E,
                                 const int* __restrict__ ntype, int* __restrict__ tcnt, int n) {
    __shared__ int lc[NT];
    int tid = threadIdx.x;
    if (tid < NT) lc[tid] = 0;
    __syncthreads();
    int gid = blockIdx.x * 256 + tid;
    if (gid < E) atomicAdd(&counts[dst[gid]], 1);
    if (gid < n) atomicAdd(&lc[ntype[gid]], 1);
    __syncthreads();
    if (tid < NT && lc[tid] > 0) atomicAdd(&tcnt[tid], lc[tid]);
}

// ---- prep: build Wcat (bf16 hi/lo, transposed [t][n][k]) + type-CSR setup ----
__global__ void prep_kernel(const float* __restrict__ Wt, const float* __restrict__ Wres,
                            const float* __restrict__ alw, const float* __restrict__ arw,
                            const int* __restrict__ tcnt, int* __restrict__ tstart,
                            int* __restrict__ pb,
                            __bf16* __restrict__ Whi, __bf16* __restrict__ Wlo) {
    int t = blockIdx.x;
    int tid = threadIdx.x;
    __shared__ float alv[HID], arv[HID];
    if (tid < 64) {
        int which = tid >= HID;
        int i = tid & (HID - 1);
        const float* p = (which ? arw : alw) + ((size_t)t * HID + i) * HID;
        float s = 0.f;
        for (int j = 0; j < HID; ++j) s += p[j];
        (which ? arv : alv)[i] = s;
    }
    if (t == 0 && tid == 255) {
        int s = 0, b = 0;
        for (int tt = 0; tt < NT; ++tt) {
            tstart[tt] = s;
            pb[tt] = b;
            s += tcnt[tt];
            b += (tcnt[tt] + BPN - 1) / BPN;
        }
        tstart[NT] = s;
        pb[NT] = b;
    }
    __syncthreads();
    for (int idx = tid; idx < NCOLS * IN_DIM; idx += 256) {
        int n = idx >> 7, k = idx & 127;
        float w;
        if (n < 128) {
            w = Wt[((size_t)t * IN_DIM + k) * OUT_DIM + n];
        } else if (n < 256) {
            w = Wres[(size_t)k * OUT_DIM + (n - 128)];
        } else if (n < 264) {
            int h = (n - 256) & 3;
            const float* av = (n >= 260) ? arv : alv;
            float s = 0.f;
            for (int i = 0; i < HID; ++i)
                s += Wt[((size_t)t * IN_DIM + k) * OUT_DIM + h * HID + i] * av[i];
            w = s;
        } else {
            w = 0.f;
        }
        __bf16 hi = (__bf16)w;
        __bf16 lo = (__bf16)(w - (float)hi);
        size_t o = ((size_t)t * NCOLS + n) * IN_DIM + k;
        Whi[o] = hi;
        Wlo[o] = lo;
    }
}

__global__ void type_scatter_kernel(const int* __restrict__ ntype, const int* __restrict__ tstart,
                                    int* __restrict__ tcur, int* __restrict__ order, int n) {
    __shared__ int lc[NT];
    __shared__ int gb[NT];
    int tid = threadIdx.x;
    if (tid < NT) lc[tid] = 0;
    __syncthreads();
    int gid = blockIdx.x * 256 + tid;
    int t = -1, rank = 0;
    if (gid < n) {
        t = ntype[gid];
        rank = atomicAdd(&lc[t], 1);
    }
    __syncthreads();
    if (tid < NT && lc[tid] > 0) gb[tid] = atomicAdd(&tcur[tid], lc[tid]);
    __syncthreads();
    if (gid < n) order[tstart[t] + gb[t] + rank] = gid;
}

// ---- node projection via split-bf16 MFMA, 64 rows/block ----
// 256 threads = 4 waves; wave w owns col tiles {4w..4w+3}, wave 3 also tile 16 (hl/hr).
// 2-term split (x_hi + x_lo) @ W_bf16; tile 16 adds x_hi @ W_lo for logit accuracy.
// mfma_f32_16x16x32_bf16: A row=lane&15, k=(lane>>4)*8+j; D col=lane&15, row=(lane>>4)*4+reg.
__global__ void __launch_bounds__(256) node_proj_mfma_kernel(
        const float* __restrict__ x, const int* __restrict__ order,
        const int* __restrict__ tstart, const int* __restrict__ tcnt,
        const int* __restrict__ pb,
        const __bf16* __restrict__ Whi, const __bf16* __restrict__ Wlo,
        const float* __restrict__ bres,
        __bf16* __restrict__ h_bf, float* __restrict__ hl, float* __restrict__ hr,
        float* __restrict__ out) {
    __shared__ __bf16 xs_hi[BPN][IN_DIM + XPAD];
    __shared__ __bf16 xs_lo[BPN][IN_DIM + XPAD];
    __shared__ int nids[BPN];
    __shared__ int spb[NT + 1];
    int tid = threadIdx.x;
    if (tid < NT + 1) spb[tid] = pb[tid];
    __syncthreads();
    int b = blockIdx.x;
    if (b >= spb[NT]) return;
    int t = 0;
    while (b >= spb[t + 1]) ++t;
    int base = (b - spb[t]) * BPN;
    int cnt = tcnt[t], ts = tstart[t];
    if (tid < BPN) nids[tid] = (base + tid < cnt) ? order[ts + base + tid] : -1;
    __syncthreads();

    for (int idx = tid; idx < BPN * (IN_DIM / 4); idx += 256) {
        int row = idx >> 5, c4 = idx & 31;
        int n = nids[row];
        float4 v = make_float4(0.f, 0.f, 0.f, 0.f);
        if (n >= 0) v = ((const float4*)(x + (size_t)n * IN_DIM))[c4];
        __bf16 h0 = (__bf16)v.x, h1 = (__bf16)v.y, h2 = (__bf16)v.z, h3 = (__bf16)v.w;
        xs_hi[row][c4 * 4 + 0] = h0;
        xs_hi[row][c4 * 4 + 1] = h1;
        xs_hi[row][c4 * 4 + 2] = h2;
        xs_hi[row][c4 * 4 + 3] = h3;
        xs_lo[row][c4 * 4 + 0] = (__bf16)(v.x - (float)h0);
        xs_lo[row][c4 * 4 + 1] = (__bf16)(v.y - (float)h1);
        xs_lo[row][c4 * 4 + 2] = (__bf16)(v.z - (float)h2);
        xs_lo[row][c4 * 4 + 3] = (__bf16)(v.w - (float)h3);
    }
    __syncthreads();

    int w = tid >> 6, lane = tid & 63;
    int lr = lane & 15, lg = lane >> 4;
    bool w3 = (w == 3);

    f32x4 acc[4][5];
#pragma unroll
    for (int m = 0; m < 4; ++m)
#pragma unroll
        for (int nt = 0; nt < 5; ++nt) acc[m][nt] = (f32x4)0.f;

    const __bf16* Wbh = Whi + (size_t)t * NCOLS * IN_DIM;
    const __bf16* Wbl = Wlo + (size_t)t * NCOLS * IN_DIM;

#pragma unroll
    for (int ks = 0; ks < 4; ++ks) {
        int kb = ks * 32 + lg * 8;
        bf16x8 ah[4], al[4];
#pragma unroll
        for (int m = 0; m < 4; ++m) {
            ah[m] = *(const bf16x8*)&xs_hi[m * 16 + lr][kb];
            al[m] = *(const bf16x8*)&xs_lo[m * 16 + lr][kb];
        }
#pragma unroll
        for (int nt = 0; nt < 5; ++nt) {
            if (nt == 4 && !w3) continue;
            int ng = (nt < 4) ? (w * 4 + nt) : 16;
            size_t wo = (size_t)(ng * 16 + lr) * IN_DIM + kb;
            bf16x8 bh = *(const bf16x8*)(Wbh + wo);
#pragma unroll
            for (int m = 0; m < 4; ++m) {
                acc[m][nt] = __builtin_amdgcn_mfma_f32_16x16x32_bf16(al[m], bh, acc[m][nt], 0, 0, 0);
                acc[m][nt] = __builtin_amdgcn_mfma_f32_16x16x32_bf16(ah[m], bh, acc[m][nt], 0, 0, 0);
            }
            if (nt == 4) {
                bf16x8 bl = *(const bf16x8*)(Wbl + wo);
#pragma unroll
                for (int m = 0; m < 4; ++m)
                    acc[m][4] = __builtin_amdgcn_mfma_f32_16x16x32_bf16(ah[m], bl, acc[m][4], 0, 0, 0);
            }
        }
    }

#pragma unroll
    for (int nt = 0; nt < 5; ++nt) {
        if (nt == 4 && !w3) continue;
        int ng = (nt < 4) ? (w * 4 + nt) : 16;
        int col = ng * 16 + lr;
        float bb = (col >= 128 && col < 256) ? bres[col - 128] : 0.f;
#pragma unroll
        for (int m = 0; m < 4; ++m) {
#pragma unroll
            for (int r = 0; r < 4; ++r) {
                int brow = m * 16 + lg * 4 + r;
                int nid = nids[brow];
                if (nid < 0) continue;
                float v = acc[m][nt][r];
                if (col < 128) {
                    h_bf[(size_t)nid * OUT_DIM + col] = (__bf16)v;
                } else if (col < 256) {
                    out[(size_t)nid * OUT_DIM + (col - 128)] = v + bb;
                } else if (col < 260) {
                    hl[nid * NH + (col - 256)] = v;
                } else if (col < 264) {
                    hr[nid * NH + (col - 260)] = v;
                }
            }
        }
    }
}

// ---- scans ----
__global__ void scan1_kernel(const int* __restrict__ counts, int* __restrict__ offs,
                             int* __restrict__ bsums, int n) {
    __shared__ int tmp[256];
    int tid = threadIdx.x, gid = blockIdx.x * 256 + tid;
    int v = (gid < n) ? counts[gid] : 0;
    tmp[tid] = v;
    __syncthreads();
    for (int o = 1; o < 256; o <<= 1) {
        int add = (tid >= o) ? tmp[tid - o] : 0;
        __syncthreads();
        tmp[tid] += add;
        __syncthreads();
    }
    if (gid < n) offs[gid] = tmp[tid] - v;
    if (tid == 255) bsums[blockIdx.x] = tmp[255];
}

__global__ void scan2_kernel(int* __restrict__ bsums, int nb) {
    __shared__ int tmp[256];
    int tid = threadIdx.x;
    int v = (tid < nb) ? bsums[tid] : 0;
    tmp[tid] = v;
    __syncthreads();
    for (int o = 1; o < 256; o <<= 1) {
        int add = (tid >= o) ? tmp[tid - o] : 0;
        __syncthreads();
        tmp[tid] += add;
        __syncthreads();
    }
    if (tid < nb) bsums[tid] = tmp[tid] - v;
}

__global__ void scan3_kernel(int* __restrict__ offs, const int* __restrict__ bsums, int n) {
    int gid = blockIdx.x * 256 + threadIdx.x;
    if (gid < n) offs[gid] += bsums[blockIdx.x];
}

// ---- scatter edges into CSR-by-dst; pre-gather hl[src] ----
__global__ void scatter_kernel(const int* __restrict__ src, const int* __restrict__ dst,
                               const int* __restrict__ offs, int* __restrict__ cursor,
                               const float4* __restrict__ hl4, int* __restrict__ src_sorted,
                               float4* __restrict__ el_sorted, int E) {
    int e = blockIdx.x * 256 + threadIdx.x;
    if (e >= E) return;
    int d = dst[e];
    int pos = offs[d] + atomicAdd(&cursor[d], 1);
    int sv = src[e];
    src_sorted[pos] = sv;
    el_sorted[pos] = hl4[sv];
}

// ---- agg: 16 lanes per node; bf16 h gathers ----
__global__ void agg_kernel(const int* __restrict__ offs, const int* __restrict__ counts,
                           const int* __restrict__ src_sorted, const float4* __restrict__ el4,
                           const float4* __restrict__ hr4, const __bf16* __restrict__ h_bf,
                           float* __restrict__ out, int n_nodes) {
    int gid = blockIdx.x * 256 + threadIdx.x;
    int n = gid >> 4;
    if (n >= n_nodes) return;
    int l = threadIdx.x & 15;
    int myh = l >> 2;
    int ofs = offs[n], deg = counts[n];
    float acc[8];
#pragma unroll
    for (int m = 0; m < 8; ++m) acc[m] = 0.f;

    if (deg > 0) {
        float4 hv = hr4[n];
        float m0 = -3e38f, m1 = -3e38f, m2 = -3e38f, m3 = -3e38f;
        for (int k = l; k < deg; k += 16) {
            float4 el = el4[ofs + k];
            m0 = fmaxf(m0, leaky(el.x + hv.x));
            m1 = fmaxf(m1, leaky(el.y + hv.y));
            m2 = fmaxf(m2, leaky(el.z + hv.z));
            m3 = fmaxf(m3, leaky(el.w + hv.w));
        }
#pragma unroll
        for (int o = 1; o < 16; o <<= 1) {
            m0 = fmaxf(m0, __shfl_xor(m0, o));
            m1 = fmaxf(m1, __shfl_xor(m1, o));
            m2 = fmaxf(m2, __shfl_xor(m2, o));
            m3 = fmaxf(m3, __shfl_xor(m3, o));
        }
        float s0 = 0.f, s1 = 0.f, s2 = 0.f, s3 = 0.f;
        for (int k = l; k < deg; k += 16) {
            float4 el = el4[ofs + k];
            s0 += __expf(leaky(el.x + hv.x) - m0);
            s1 += __expf(leaky(el.y + hv.y) - m1);
            s2 += __expf(leaky(el.z + hv.z) - m2);
            s3 += __expf(leaky(el.w + hv.w) - m3);
        }
#pragma unroll
        for (int o = 1; o < 16; o <<= 1) {
            s0 += __shfl_xor(s0, o);
            s1 += __shfl_xor(s1, o);
            s2 += __shfl_xor(s2, o);
            s3 += __shfl_xor(s3, o);
        }
        float mh  = myh < 2 ? (myh == 0 ? m0 : m1) : (myh == 2 ? m2 : m3);
        float sh  = myh < 2 ? (myh == 0 ? s0 : s1) : (myh == 2 ? s2 : s3);
        float hrh = myh < 2 ? (myh == 0 ? hv.x : hv.y) : (myh == 2 ? hv.z : hv.w);
        float inv_s = 1.f / sh;

        const float* elf = (const float*)el4;
        int k = 0;
        for (; k + 2 <= deg; k += 2) {
            int sv0 = src_sorted[ofs + k];
            int sv1 = src_sorted[ofs + k + 1];
            float e0 = elf[(size_t)(ofs + k) * 4 + myh];
            float e1 = elf[(size_t)(ofs + k + 1) * 4 + myh];
            uint4 u0 = *(const uint4*)(h_bf + (size_t)sv0 * OUT_DIM + l * 8);
            uint4 u1 = *(const uint4*)(h_bf + (size_t)sv1 * OUT_DIM + l * 8);
            float a0 = __expf(leaky(e0 + hrh) - mh) * inv_s;
            float a1 = __expf(leaky(e1 + hrh) - mh) * inv_s;
            acc[0] += a0 * blo(u0.x); acc[1] += a0 * bhi(u0.x);
            acc[2] += a0 * blo(u0.y); acc[3] += a0 * bhi(u0.y);
            acc[4] += a0 * blo(u0.z); acc[5] += a0 * bhi(u0.z);
            acc[6] += a0 * blo(u0.w); acc[7] += a0 * bhi(u0.w);
            acc[0] += a1 * blo(u1.x); acc[1] += a1 * bhi(u1.x);
            acc[2] += a1 * blo(u1.y); acc[3] += a1 * bhi(u1.y);
            acc[4] += a1 * blo(u1.z); acc[5] += a1 * bhi(u1.z);
            acc[6] += a1 * blo(u1.w); acc[7] += a1 * bhi(u1.w);
        }
        if (k < deg) {
            int sv0 = src_sorted[ofs + k];
            float e0 = elf[(size_t)(ofs + k) * 4 + myh];
            uint4 u0 = *(const uint4*)(h_bf + (size_t)sv0 * OUT_DIM + l * 8);
            float a0 = __expf(leaky(e0 + hrh) - mh) * inv_s;
            acc[0] += a0 * blo(u0.x); acc[1] += a0 * bhi(u0.x);
            acc[2] += a0 * blo(u0.y); acc[3] += a0 * bhi(u0.y);
            acc[4] += a0 * blo(u0.z); acc[5] += a0 * bhi(u0.z);
            acc[6] += a0 * blo(u0.w); acc[7] += a0 * bhi(u0.w);
        }
    }
    // h dword i = l*8+m -> (head = l>>2, d = (l&3)*8+m) -> out col j = d*4+head
    size_t ob = (size_t)n * OUT_DIM;
    int based = (l & 3) << 3;
#pragma unroll
    for (int m = 0; m < 8; ++m) {
        int j = ((based + m) << 2) | myh;
        out[ob + j] = fmaxf(acc[m] + out[ob + j], 0.f);
    }
}

extern "C" void kernel_launch(void* const* d_in, const int* in_sizes, int n_in,
                              void* d_out, int out_size, void* d_ws, size_t ws_size,
                              hipStream_t stream) {
    const float* x     = (const float*)d_in[0];
    const int*   ntype = (const int*)d_in[1];
    const int*   src   = (const int*)d_in[3];
    const int*   dst   = (const int*)d_in[4];
    const float* Wt    = (const float*)d_in[5];
    const float* alw   = (const float*)d_in[6];
    const float* arw   = (const float*)d_in[7];
    const float* Wres  = (const float*)d_in[8];
    const float* bres  = (const float*)d_in[9];
    float* out = (float*)d_out;
    int N = in_sizes[1];
    int E = in_sizes[3];

    char* ws = (char*)d_ws;
    size_t off = 0;
    auto alloc = [&](size_t bytes) -> char* {
        char* p = ws + off;
        off += (bytes + 255) & ~(size_t)255;
        return p;
    };
    __bf16* h_bf       = (__bf16*)alloc((size_t)N * OUT_DIM * 2);
    float*  hl         = (float*)alloc((size_t)N * NH * 4);
    float*  hr         = (float*)alloc((size_t)N * NH * 4);
    int*    offs       = (int*)alloc((size_t)N * 4);
    int*    bsums      = (int*)alloc(256 * 4);
    int*    src_sorted = (int*)alloc((size_t)E * 4);
    float4* el_sorted  = (float4*)alloc((size_t)E * 16);
    int*    tstart     = (int*)alloc((NT + 1) * 4);
    int*    pb         = (int*)alloc((NT + 1) * 4);
    int*    order      = (int*)alloc((size_t)N * 4);
    __bf16* Whi        = (__bf16*)alloc((size_t)NT * NCOLS * IN_DIM * 2);
    __bf16* Wlo        = (__bf16*)alloc((size_t)NT * NCOLS * IN_DIM * 2);
    // zero-initialized group (single memset)
    char*   zstart     = ws + off;
    int*    counts     = (int*)alloc((size_t)N * 4);
    int*    cursor     = (int*)alloc((size_t)N * 4);
    int*    tcnt       = (int*)alloc(NT * 4);
    int*    tcur       = (int*)alloc(NT * 4);
    size_t  zlen       = (ws + off) - zstart;

    hipMemsetAsync(zstart, 0, zlen, stream);

    int nbs = (N + 255) / 256;
    int nbe = (E + 255) / 256;

    hist_both_kernel<<<nbe, 256, 0, stream>>>(dst, counts, E, ntype, tcnt, N);
    prep_kernel<<<NT, 256, 0, stream>>>(Wt, Wres, alw, arw, tcnt, tstart, pb, Whi, Wlo);
    type_scatter_kernel<<<nbs, 256, 0, stream>>>(ntype, tstart, tcur, order, N);

    int nb1 = (N + BPN - 1) / BPN + NT;
    node_proj_mfma_kernel<<<nb1, 256, 0, stream>>>(x, order, tstart, tcnt, pb,
                                                   Whi, Wlo, bres, h_bf, hl, hr, out);

    scan1_kernel<<<nbs, 256, 0, stream>>>(counts, offs, bsums, N);
    scan2_kernel<<<1, 256, 0, stream>>>(bsums, nbs);
    scan3_kernel<<<nbs, 256, 0, stream>>>(offs, bsums, N);

    scatter_kernel<<<nbe, 256, 0, stream>>>(src, dst, offs, cursor,
                                            (const float4*)hl, src_sorted, el_sorted, E);

    agg_kernel<<<(N * 16 + 255) / 256, 256, 0, stream>>>(offs, counts, src_sorted,
                                                         (const float4*)el_sorted,
                                                         (const float4*)hr, h_bf, out, N);
}